// Round 20
// baseline (69.618 us; speedup 1.0000x reference)
//
#include <hip/hip_runtime.h>

// LSHAttention: reference returns ONLY sticker = argsort(buckets) [B,S] int32.
// B=4, S=4096, D=1024, NR=32, 64 buckets.
//
// ROUND 20: depth-2 prefetch + 4 blocks/CU + proven no-spill footprint, all
// at once (every prior round had at most one of the three; congestion-latency
// stall = eff_latency(~2-3Kcyc) - 1-tile compute(~1Kcyc) per tile was never
// covered). K-split 8 ways: R slice 16 KB static + 4 waves x 3 x 2 KB Q bufs
// = 40 KB LDS -> 4 blocks/CU = 16 waves/CU. Barrier-free main loop
// (R read-only, Q wave-private), per-wave counted vmcnt(4/2/0) with tiles
// tau+1, tau+2 permanently in flight. waves_per_eu(4,4) = the setting that
// allocated this exact compute shape at 84 VGPR spill-free (R11/R16).
//
// k1: grid 2048 = (b:4, chunk:64 -> 64 tok, kqr:8 -> 128 k), 256 thr = 4 waves.
//   Wave w owns tokens [w*16,w*16+16); 4 tiles of 32 k.
//   Lane = (tok_t:2 x8tok, r_t:4 x8r, kl:8); acc = 8tok x 8r = 64 f32.
//   LDS layouts (T21 both-sides: linear DMA dst + inverse-swizzled src +
//   swizzled read; cancellation hand-verified):
//     R slot = kh*8 + (v ^ ((kh>>2)&7)); read grp (r_t*2+p)^kl -> 4-way (=R17).
//     Q slot = td*8 + (sd ^ (td>>3));   read grp kl^tok_t -> 2-way = free.
//   Epilogue: kl-butterfly(1,2,4); kl==0 lanes store P[b][chunk][kqr][64][32].
// k1c: 256 blocks: sum 8 K-slices -> argmax -> buckets + 64-chunk hist.
// k2/k3: 64-token-chunk scan + stable scatter (verified round 1, verbatim).

#define B_DIM 4
#define S_LEN 4096
#define D_DIM 1024
#define NRR 32
#define NBK 64
#define TMK 64                  // tokens per chunk (= hist chunk)
#define NCHUNK (S_LEN / TMK)    // 64
#define NKQ 8                   // K slices of 128
#define QOFF 1024               // f4 offset of Q buffers (R slice = 1024 f4)
#define PSL 2048                // f32 per partial slice: 64 tok x 32 r

typedef const __attribute__((address_space(1))) void* gas_t;
typedef __attribute__((address_space(3))) void* las_t;

#define FMA4(A, S, B)                                                        \
    (A).x = fmaf((S), (B).x, (A).x); (A).y = fmaf((S), (B).y, (A).y);        \
    (A).z = fmaf((S), (B).z, (A).z); (A).w = fmaf((S), (B).w, (A).w);

__global__ void __launch_bounds__(256) __attribute__((amdgpu_waves_per_eu(4, 4)))
k1_gemm(const float* __restrict__ Q, const float* __restrict__ R,
        float4* __restrict__ P4)
{
    __shared__ float4 smem4[QOFF + 1536];   // R 16KB + 4w x 3buf x 128 f4 = 40KB

    const int bid = blockIdx.x;
    const int kqr = bid & 7;
    const int chunk = (bid >> 3) & 63;
    const int b = bid >> 9;

    const int t = threadIdx.x;
    const int w = t >> 6;
    const int lane = t & 63;
    const int tok_t = lane >> 5;         // 2 groups x 8 tokens
    const int r_t = (lane >> 3) & 3;     // 4 groups x 8 r (2 f4)
    const int kl = lane & 7;             // 8-way k split

    const float4* Qw4 = (const float4*)(Q + ((size_t)b * S_LEN + chunk * TMK + w * 16) * D_DIM);
    const float4* Rg4 = (const float4*)(R + (size_t)b * D_DIM * NRR);

    // ---- R slice stage: linear dst, inverse-swizzled src (sigma = kh&..) ----
#define STAGE_R()                                                             \
    {                                                                         \
        _Pragma("unroll")                                                     \
        for (int i = 0; i < 4; ++i) {                                         \
            const int f = w * 256 + i * 64 + lane;                            \
            const int kh = f >> 3, v = f & 7;                                 \
            __builtin_amdgcn_global_load_lds(                                 \
                (gas_t)(Rg4 + ((size_t)kqr * 128 + kh) * 8 + (v ^ ((kh >> 2) & 7))), \
                (las_t)&smem4[w * 256 + i * 64], 16, 0, 0);                   \
        }                                                                     \
    }

    // ---- Q tile stage (2 KB/wave): linear dst, inverse-swizzled src ----
#define ISSUE_Q(TILE, DST)                                                    \
    {                                                                         \
        _Pragma("unroll")                                                     \
        for (int i = 0; i < 2; ++i) {                                         \
            const int f = i * 64 + lane;                                      \
            const int td = f >> 3, sd = f & 7;                                \
            __builtin_amdgcn_global_load_lds(                                 \
                (gas_t)(Qw4 + (size_t)td * 256 + kqr * 32 + (TILE) * 8        \
                        + (sd ^ (td >> 3))),                                  \
                (las_t)&smem4[QOFF + w * 384 + (DST) * 128 + i * 64], 16, 0, 0);\
        }                                                                     \
    }

#define COMPUTE(TILE, BUF)                                                    \
    {                                                                         \
        const float4* qb = smem4 + QOFF + w * 384 + (BUF) * 128;              \
        const float4* rb = smem4;                                             \
        float4 rv[4][2];                                                      \
        _Pragma("unroll")                                                     \
        for (int c = 0; c < 4; ++c) {                                         \
            const int krow = (TILE) * 32 + kl * 4 + c;                        \
            rv[c][0] = rb[krow * 8 + ((r_t * 2 + 0) ^ kl)];                   \
            rv[c][1] = rb[krow * 8 + ((r_t * 2 + 1) ^ kl)];                   \
        }                                                                     \
        _Pragma("unroll")                                                     \
        for (int j = 0; j < 8; ++j) {                                         \
            const float4 qv = qb[(tok_t * 8 + j) * 8 + (kl ^ tok_t)];         \
            _Pragma("unroll")                                                 \
            for (int c = 0; c < 4; ++c) {                                     \
                const float s = c == 0 ? qv.x : c == 1 ? qv.y                 \
                              : c == 2 ? qv.z : qv.w;                         \
                FMA4(acc[j][0], s, rv[c][0]);                                 \
                FMA4(acc[j][1], s, rv[c][1]);                                 \
            }                                                                 \
        }                                                                     \
    }

    float4 acc[8][2];
#pragma unroll
    for (int j = 0; j < 8; ++j) {
        acc[j][0] = make_float4(0.f, 0.f, 0.f, 0.f);
        acc[j][1] = make_float4(0.f, 0.f, 0.f, 0.f);
    }

    // ---- prologue: R slice + Q tiles 0,1; the only barrier ----
    STAGE_R()
    ISSUE_Q(0, 0)
    ISSUE_Q(1, 1)
    asm volatile("s_waitcnt vmcnt(0)" ::: "memory");
    __syncthreads();

    // ---- barrier-free main loop, tiles tau+1 & tau+2 always in flight ----
    ISSUE_Q(2, 2)
    COMPUTE(0, 0)
    asm volatile("s_waitcnt lgkmcnt(0)" ::: "memory");   // buf0 reads done
    ISSUE_Q(3, 0)
    COMPUTE(1, 1)                                        // tile1 drained in prologue
    asm volatile("s_waitcnt vmcnt(2)" ::: "memory");     // tile2 landed (tile3 in flight)
    COMPUTE(2, 2)
    asm volatile("s_waitcnt vmcnt(0)" ::: "memory");     // tile3 landed
    COMPUTE(3, 0)
#undef STAGE_R
#undef ISSUE_Q
#undef COMPUTE

    // ---- butterfly reduce over kl (lane bits 0-2) ----
#pragma unroll
    for (int j = 0; j < 8; ++j)
#pragma unroll
        for (int p = 0; p < 2; ++p)
#pragma unroll
            for (int off = 1; off < 8; off <<= 1) {
                acc[j][p].x += __shfl_xor(acc[j][p].x, off, 64);
                acc[j][p].y += __shfl_xor(acc[j][p].y, off, 64);
                acc[j][p].z += __shfl_xor(acc[j][p].z, off, 64);
                acc[j][p].w += __shfl_xor(acc[j][p].w, off, 64);
            }

    // ---- kl==0 lanes hold full slice-sums: store partial slice ----
    if (kl == 0) {
        float4* Pb = P4 + (((size_t)b * NCHUNK + chunk) * NKQ + kqr) * (PSL / 4);
#pragma unroll
        for (int j = 0; j < 8; ++j) {
            const int tok = w * 16 + tok_t * 8 + j;
            Pb[tok * 8 + r_t * 2 + 0] = acc[j][0];
            Pb[tok * 8 + r_t * 2 + 1] = acc[j][1];
        }
    }
}

// 256 blocks = (b, 64-token chunk): sum 8 K-slices, argmax, bucket, hist.
__global__ __launch_bounds__(256) void k1c_combine(
    const float* __restrict__ P,
    int* __restrict__ buckets, int* __restrict__ hist)
{
    __shared__ float xs[TMK][NRR + 1];
    __shared__ int cnt[NBK];

    const int bid = blockIdx.x;
    const int b = bid >> 6;
    const int h = bid & 63;
    const int t = threadIdx.x;

    const float* Pb = P + ((size_t)b * NCHUNK + h) * NKQ * PSL;
#pragma unroll
    for (int i = 0; i < 8; ++i) {
        const int idx = t + 256 * i;          // 0..2047 = 64 tok x 32 r
        const int tok = idx >> 5, r = idx & 31;
        const size_t base = (size_t)tok * NRR + r;
        float s = 0.f;
#pragma unroll
        for (int ks = 0; ks < NKQ; ++ks) s += Pb[base + (size_t)ks * PSL];
        xs[tok][r] = s;
    }
    if (t < NBK) cnt[t] = 0;
    __syncthreads();

    if (t < TMK) {
        // argmax(concat[xR,-xR]) with first-occurrence tie-break
        float m1 = xs[t][0]; int i1 = 0;
        float m2 = m1;       int i2 = 0;
#pragma unroll
        for (int r = 1; r < NRR; ++r) {
            const float v = xs[t][r];
            if (v > m1) { m1 = v; i1 = r; }
            if (v < m2) { m2 = v; i2 = r; }
        }
        const int bk = (m1 >= -m2) ? i1 : (NRR + i2);
        buckets[(size_t)b * S_LEN + h * TMK + t] = bk;
        atomicAdd(&cnt[bk], 1);
    }
    __syncthreads();
    if (t < NBK) hist[((size_t)b * NCHUNK + h) * NBK + t] = cnt[t];
}

// One block, 256 threads: thread = (batch b = t/64, bucket bk = t%64).
__global__ __launch_bounds__(256) void k2_scan(
    const int* __restrict__ hist, int* __restrict__ chunkOffset)
{
    const int t = threadIdx.x;
    const int b = t >> 6;
    const int bk = t & 63;
    const int lane = t & 63;

    int total = 0;
    for (int c = 0; c < NCHUNK; ++c)
        total += hist[((size_t)b * NCHUNK + c) * NBK + bk];

    int incl = total;
#pragma unroll
    for (int off = 1; off < 64; off <<= 1) {
        int n = __shfl_up(incl, off, 64);
        if (lane >= off) incl += n;
    }
    int run = incl - total;   // exclusive prefix over buckets = bucketStart

    for (int c = 0; c < NCHUNK; ++c) {
        int h = hist[((size_t)b * NCHUNK + c) * NBK + bk];
        chunkOffset[((size_t)b * NCHUNK + c) * NBK + bk] = run;
        run += h;
    }
}

// Stable scatter: wave = 64 consecutive tokens (one chunk).
__global__ __launch_bounds__(256) void k3_scatter(
    const int* __restrict__ buckets, const int* __restrict__ chunkOffset,
    int* __restrict__ out)
{
    const int gid = blockIdx.x * 256 + threadIdx.x;  // 0..16383
    const int b = gid >> 12;
    const int s = gid & (S_LEN - 1);
    const int chunk = s >> 6;
    const int lane = threadIdx.x & 63;

    const int bk = buckets[gid];

    unsigned long long m = ~0ull;
#pragma unroll
    for (int i = 0; i < 6; ++i) {
        unsigned long long bi = __ballot((bk >> i) & 1);
        m &= ((bk >> i) & 1) ? bi : ~bi;
    }
    int rank = __popcll(m & ((1ull << lane) - 1ull));

    int pos = chunkOffset[((size_t)b * NCHUNK + chunk) * NBK + bk] + rank;
    out[(size_t)b * S_LEN + pos] = s;
}

extern "C" void kernel_launch(void* const* d_in, const int* in_sizes, int n_in,
                              void* d_out, int out_size, void* d_ws, size_t ws_size,
                              hipStream_t stream) {
    const float* Q = (const float*)d_in[0];
    // d_in[1] = key, d_in[2] = value: dead code in the reference, never read.
    const float* R = (const float*)d_in[3];

    float* P         = (float*)d_ws;   // 4*64*8*2048 f32 = 16 MB partials
    int* buckets     = (int*)(P + (size_t)B_DIM * NCHUNK * NKQ * PSL);
    int* hist        = buckets + B_DIM * S_LEN;
    int* chunkOffset = hist + B_DIM * NCHUNK * NBK;

    k1_gemm    <<<B_DIM * NCHUNK * NKQ, 256, 0, stream>>>(Q, R, (float4*)P);
    k1c_combine<<<B_DIM * NCHUNK,       256, 0, stream>>>(P, buckets, hist);
    k2_scan    <<<1,                    256, 0, stream>>>(hist, chunkOffset);
    k3_scatter <<<(B_DIM * S_LEN) / 256, 256, 0, stream>>>(buckets, chunkOffset, (int*)d_out);
}